// Round 5
// baseline (265.685 us; speedup 1.0000x reference)
//
#include <hip/hip_runtime.h>
#include <hip/hip_bf16.h>
#include <stdint.h>

// Problem constants (from reference)
#define IN_F   1024
#define OUT_F  1024
#define NLEAF  16
#define BATCH  4096

// GEMM C'[n, b] = sum_i W'[n,i] * Xb[b,i],  n = o*16+l  (n = C-tile ROW dim).
// R10: fully pre-issued fragment pipeline.  All 12 ds_reads of tile t+1
// issue DURING tile t (a-reads between c1 and c2, b/x-reads pre-barrier),
// so after each barrier the critical path is lgkmcnt(4) (usually satisfied)
// -> c1 starts immediately.  In-order DS returns make counted waits exact:
//   entry: outstanding [a,b,x](12) -> lgk(4) drains a,b (c1 operands)
//   after READS_A4:    [x,a'](8)   -> lgk(4) drains x   (c2 operands)
// WAR: a re-read only after c1 consumed it; b,x after c2.  Publication:
// VM4 at tile t-1 lands stage(t+1) before barrier(t-1) -> reads(t+1) in
// tile t are race-free.  Slot re-stage at t+4 >> reads drained at t.
#define KK      1024              // GEMM K = IN_F
#define NN      (OUT_F * NLEAF)   // 16384
#define BM      256               // n-tile
#define BN      256               // b-tile
#define BK      32
#define NKT     (KK / BK)         // 32 K-tiles
#define ABYTES  (BM * BK * 2)     // 16 KB per operand tile
#define SLICE   (2 * ABYTES)      // 32 KB (A+B) per ring slot; 4 slots = 128 KB
#define GS_PAD  257               // g-tile LDS row stride (conflict-free quads)

typedef __bf16 bf16x8 __attribute__((ext_vector_type(8)));
typedef float  f32x4  __attribute__((ext_vector_type(4)));

#define ASYNC_COPY16(gp, lp)                                                         \
  __builtin_amdgcn_global_load_lds((const __attribute__((address_space(1))) void*)(gp), \
                                   (__attribute__((address_space(3))) void*)(lp),       \
                                   16, 0, 0)

#define VM4  asm volatile("s_waitcnt vmcnt(4)" ::: "memory")
#define VM0  asm volatile("s_waitcnt vmcnt(0)" ::: "memory")
#define VM8  asm volatile("s_waitcnt vmcnt(8)" ::: "memory")
#define NOVM ((void)0)

// ---------------------------------------------------------------------------
// Kernel 1: fused prep.  Blocks [0,1024): transpose/pack pw -> W'.
// Blocks [1024,2048): gating softmax + x->bf16 pack (4 batch rows/block).
// ---------------------------------------------------------------------------
__global__ __launch_bounds__(256) void prep_kernel(
    const float* __restrict__ x, const float* __restrict__ gw,
    const float* __restrict__ gb, const float* __restrict__ pw,
    float* __restrict__ g, __hip_bfloat16* __restrict__ xb,
    __hip_bfloat16* __restrict__ W) {
  __shared__ __align__(16) __hip_bfloat16 lt[16 * 264];
  const int t = threadIdx.x;

  if (blockIdx.x < OUT_F) {
    // ---- pack_w path: W'[o*16+l, i] = bf16(pw[o,i,l]) via LDS transpose ----
    const int o = blockIdx.x;
    const float* src = pw + (size_t)o * (IN_F * NLEAF);
    for (int ch = 0; ch < 4; ++ch) {
      const float4* p = (const float4*)(src + ch * 4096 + t * 16);  // i=t, 16 l
      const float4 v0 = p[0], v1 = p[1], v2 = p[2], v3 = p[3];
      if (ch) __syncthreads();   // prev readout done before overwriting lt
      lt[ 0 * 264 + t] = __float2bfloat16(v0.x);
      lt[ 1 * 264 + t] = __float2bfloat16(v0.y);
      lt[ 2 * 264 + t] = __float2bfloat16(v0.z);
      lt[ 3 * 264 + t] = __float2bfloat16(v0.w);
      lt[ 4 * 264 + t] = __float2bfloat16(v1.x);
      lt[ 5 * 264 + t] = __float2bfloat16(v1.y);
      lt[ 6 * 264 + t] = __float2bfloat16(v1.z);
      lt[ 7 * 264 + t] = __float2bfloat16(v1.w);
      lt[ 8 * 264 + t] = __float2bfloat16(v2.x);
      lt[ 9 * 264 + t] = __float2bfloat16(v2.y);
      lt[10 * 264 + t] = __float2bfloat16(v2.z);
      lt[11 * 264 + t] = __float2bfloat16(v2.w);
      lt[12 * 264 + t] = __float2bfloat16(v3.x);
      lt[13 * 264 + t] = __float2bfloat16(v3.y);
      lt[14 * 264 + t] = __float2bfloat16(v3.z);
      lt[15 * 264 + t] = __float2bfloat16(v3.w);
      __syncthreads();
#pragma unroll
      for (int jj = 0; jj < 2; ++jj) {
        const int u = t + 256 * jj;        // 512 uint4 per chunk
        const int l = u >> 5;
        const int i8 = (u & 31) * 8;
        *(uint4*)(W + ((size_t)o * NLEAF + l) * KK + ch * 256 + i8) =
            *(const uint4*)(lt + l * 264 + i8);
      }
    }
  } else {
    // ---- gate + pack_x path ----
    const int blk  = blockIdx.x - OUT_F;
    const int lane = t & 63;
    const int wv   = t >> 6;
    const int b    = blk * 4 + wv;
    const int i4   = lane >> 4;
    const int l    = lane & 15;

    const float* xrow = x + (size_t)b * IN_F;
    float acc = 0.f;
#pragma unroll 8
    for (int k = 0; k < IN_F / 4; ++k) {
      const float xv = xrow[k * 4 + i4];          // same addr per 16-group (L1)
      const float wvv = gw[k * 64 + lane];        // coalesced
      acc = fmaf(xv, wvv, acc);
    }
    acc += __shfl_xor(acc, 16);
    acc += __shfl_xor(acc, 32);
    float logit = acc + gb[l];
    float m = logit;
#pragma unroll
    for (int off = 8; off > 0; off >>= 1) m = fmaxf(m, __shfl_xor(m, off));
    float e = __expf(logit - m);
    float s = e;
#pragma unroll
    for (int off = 8; off > 0; off >>= 1) s += __shfl_xor(s, off);
    if (lane < NLEAF) g[b * NLEAF + l] = e / s;

    const float* xblk = x + (size_t)blk * 4 * IN_F;
    __hip_bfloat16* xbblk = xb + (size_t)blk * 4 * IN_F;
#pragma unroll
    for (int j = 0; j < 2; ++j) {
      const int f = (t + 256 * j) * 8;
      const float4 a0 = *(const float4*)(xblk + f);
      const float4 a1 = *(const float4*)(xblk + f + 4);
      __align__(16) __hip_bfloat16 tmp[8];
      tmp[0] = __float2bfloat16(a0.x); tmp[1] = __float2bfloat16(a0.y);
      tmp[2] = __float2bfloat16(a0.z); tmp[3] = __float2bfloat16(a0.w);
      tmp[4] = __float2bfloat16(a1.x); tmp[5] = __float2bfloat16(a1.y);
      tmp[6] = __float2bfloat16(a1.z); tmp[7] = __float2bfloat16(a1.w);
      *(uint4*)(xbblk + f) = *(const uint4*)tmp;
    }
  }
}

// ---------------------------------------------------------------------------
// Kernel 2: bf16 MFMA GEMM, 256x256 tile, fully pre-issued 4-deep ring.
// 512 threads = 8 waves (wr in {0,1} n-dir x wc in 0..3 b-dir); per-wave
// output 128x64.  acc[mi][ni][r] = C'[n = n0 + wr*128 + mi*16 + quad*4 + r]
// [b = b0 + wc*64 + ni*16 + r16]; l = quad*4+r, o = n/16.  K-slot XOR swizzle
// for conflict-free fragment reads (counter-verified ~0 in main loop).
// ---------------------------------------------------------------------------
#define STAGE_AB(tt, SL3)                                            \
  do {                                                               \
    char* _dA = smem + (SL3) * SLICE;                                \
    char* _dB = _dA + ABYTES;                                        \
    const __hip_bfloat16* _sA = aG + (long)(tt) * BK;                \
    const __hip_bfloat16* _sB = bG + (long)(tt) * BK;                \
    ASYNC_COPY16(_sA + gOff0, _dA + c0 * 16);                        \
    ASYNC_COPY16(_sA + gOff1, _dA + c1 * 16);                        \
    ASYNC_COPY16(_sB + gOff0, _dB + c0 * 16);                        \
    ASYNC_COPY16(_sB + gOff1, _dB + c1 * 16);                        \
  } while (0)

// c1 A-fragments of tile tt (A rows wr*128 + 0..48)
#define READS_A4(tt)                                                           \
  do {                                                                         \
    const __hip_bfloat16* _As =                                                \
        (const __hip_bfloat16*)(smem + ((tt) & 3) * SLICE);                    \
    a0 = *(const bf16x8*)(_As + ((wr * 128 +  0 + r16) * 4 + (quad ^ swz)) * 8); \
    a1 = *(const bf16x8*)(_As + ((wr * 128 + 16 + r16) * 4 + (quad ^ swz)) * 8); \
    a2 = *(const bf16x8*)(_As + ((wr * 128 + 32 + r16) * 4 + (quad ^ swz)) * 8); \
    a3 = *(const bf16x8*)(_As + ((wr * 128 + 48 + r16) * 4 + (quad ^ swz)) * 8); \
  } while (0)

// B fragments + c2 A-fragments of tile tt (issued pre-barrier)
#define READS_BX8(tt)                                                          \
  do {                                                                         \
    const __hip_bfloat16* _As =                                                \
        (const __hip_bfloat16*)(smem + ((tt) & 3) * SLICE);                    \
    const __hip_bfloat16* _Bs =                                                \
        (const __hip_bfloat16*)(smem + ((tt) & 3) * SLICE + ABYTES);           \
    b0 = *(const bf16x8*)(_Bs + ((wc * 64 +  0 + r16) * 4 + (quad ^ swz)) * 8);  \
    b1 = *(const bf16x8*)(_Bs + ((wc * 64 + 16 + r16) * 4 + (quad ^ swz)) * 8);  \
    b2 = *(const bf16x8*)(_Bs + ((wc * 64 + 32 + r16) * 4 + (quad ^ swz)) * 8);  \
    b3 = *(const bf16x8*)(_Bs + ((wc * 64 + 48 + r16) * 4 + (quad ^ swz)) * 8);  \
    x0 = *(const bf16x8*)(_As + ((wr * 128 +  64 + r16) * 4 + (quad ^ swz)) * 8); \
    x1 = *(const bf16x8*)(_As + ((wr * 128 +  80 + r16) * 4 + (quad ^ swz)) * 8); \
    x2 = *(const bf16x8*)(_As + ((wr * 128 +  96 + r16) * 4 + (quad ^ swz)) * 8); \
    x3 = *(const bf16x8*)(_As + ((wr * 128 + 112 + r16) * 4 + (quad ^ swz)) * 8); \
  } while (0)

// One K-tile.  Entry regs: a,b,x = tile tt's frags (issued during tile tt-1,
// outstanding in order [a,b,x]).  lgk(4) drains a,b; after READS_A4 the
// outstanding order is [x, a'] so lgk(4) drains x.  DO_READS=0 (last tile):
// second wait is lgk(0).
#define TILE_BODY(tt, DO_STAGE, TAILVM, DO_READS)                              \
  do {                                                                         \
    if (DO_STAGE) STAGE_AB((tt) + 3, ((tt) + 3) & 3);                          \
    asm volatile("s_waitcnt lgkmcnt(4)" ::: "memory");                         \
    __builtin_amdgcn_sched_barrier(0);                                         \
    __builtin_amdgcn_s_setprio(1);                                             \
    acc[0][0] = __builtin_amdgcn_mfma_f32_16x16x32_bf16(a0, b0, acc[0][0], 0, 0, 0); \
    acc[0][1] = __builtin_amdgcn_mfma_f32_16x16x32_bf16(a0, b1, acc[0][1], 0, 0, 0); \
    acc[0][2] = __builtin_amdgcn_mfma_f32_16x16x32_bf16(a0, b2, acc[0][2], 0, 0, 0); \
    acc[0][3] = __builtin_amdgcn_mfma_f32_16x16x32_bf16(a0, b3, acc[0][3], 0, 0, 0); \
    acc[1][0] = __builtin_amdgcn_mfma_f32_16x16x32_bf16(a1, b0, acc[1][0], 0, 0, 0); \
    acc[1][1] = __builtin_amdgcn_mfma_f32_16x16x32_bf16(a1, b1, acc[1][1], 0, 0, 0); \
    acc[1][2] = __builtin_amdgcn_mfma_f32_16x16x32_bf16(a1, b2, acc[1][2], 0, 0, 0); \
    acc[1][3] = __builtin_amdgcn_mfma_f32_16x16x32_bf16(a1, b3, acc[1][3], 0, 0, 0); \
    acc[2][0] = __builtin_amdgcn_mfma_f32_16x16x32_bf16(a2, b0, acc[2][0], 0, 0, 0); \
    acc[2][1] = __builtin_amdgcn_mfma_f32_16x16x32_bf16(a2, b1, acc[2][1], 0, 0, 0); \
    acc[2][2] = __builtin_amdgcn_mfma_f32_16x16x32_bf16(a2, b2, acc[2][2], 0, 0, 0); \
    acc[2][3] = __builtin_amdgcn_mfma_f32_16x16x32_bf16(a2, b3, acc[2][3], 0, 0, 0); \
    acc[3][0] = __builtin_amdgcn_mfma_f32_16x16x32_bf16(a3, b0, acc[3][0], 0, 0, 0); \
    acc[3][1] = __builtin_amdgcn_mfma_f32_16x16x32_bf16(a3, b1, acc[3][1], 0, 0, 0); \
    acc[3][2] = __builtin_amdgcn_mfma_f32_16x16x32_bf16(a3, b2, acc[3][2], 0, 0, 0); \
    acc[3][3] = __builtin_amdgcn_mfma_f32_16x16x32_bf16(a3, b3, acc[3][3], 0, 0, 0); \
    __builtin_amdgcn_s_setprio(0);                                             \
    if (DO_READS) {                                                            \
      READS_A4((tt) + 1);                                                      \
      asm volatile("s_waitcnt lgkmcnt(4)" ::: "memory");                       \
    } else {                                                                   \
      asm volatile("s_waitcnt lgkmcnt(0)" ::: "memory");                       \
    }                                                                          \
    __builtin_amdgcn_sched_barrier(0);                                         \
    __builtin_amdgcn_s_setprio(1);                                             \
    acc[4][0] = __builtin_amdgcn_mfma_f32_16x16x32_bf16(x0, b0, acc[4][0], 0, 0, 0); \
    acc[4][1] = __builtin_amdgcn_mfma_f32_16x16x32_bf16(x0, b1, acc[4][1], 0, 0, 0); \
    acc[4][2] = __builtin_amdgcn_mfma_f32_16x16x32_bf16(x0, b2, acc[4][2], 0, 0, 0); \
    acc[4][3] = __builtin_amdgcn_mfma_f32_16x16x32_bf16(x0, b3, acc[4][3], 0, 0, 0); \
    acc[5][0] = __builtin_amdgcn_mfma_f32_16x16x32_bf16(x1, b0, acc[5][0], 0, 0, 0); \
    acc[5][1] = __builtin_amdgcn_mfma_f32_16x16x32_bf16(x1, b1, acc[5][1], 0, 0, 0); \
    acc[5][2] = __builtin_amdgcn_mfma_f32_16x16x32_bf16(x1, b2, acc[5][2], 0, 0, 0); \
    acc[5][3] = __builtin_amdgcn_mfma_f32_16x16x32_bf16(x1, b3, acc[5][3], 0, 0, 0); \
    acc[6][0] = __builtin_amdgcn_mfma_f32_16x16x32_bf16(x2, b0, acc[6][0], 0, 0, 0); \
    acc[6][1] = __builtin_amdgcn_mfma_f32_16x16x32_bf16(x2, b1, acc[6][1], 0, 0, 0); \
    acc[6][2] = __builtin_amdgcn_mfma_f32_16x16x32_bf16(x2, b2, acc[6][2], 0, 0, 0); \
    acc[6][3] = __builtin_amdgcn_mfma_f32_16x16x32_bf16(x2, b3, acc[6][3], 0, 0, 0); \
    acc[7][0] = __builtin_amdgcn_mfma_f32_16x16x32_bf16(x3, b0, acc[7][0], 0, 0, 0); \
    acc[7][1] = __builtin_amdgcn_mfma_f32_16x16x32_bf16(x3, b1, acc[7][1], 0, 0, 0); \
    acc[7][2] = __builtin_amdgcn_mfma_f32_16x16x32_bf16(x3, b2, acc[7][2], 0, 0, 0); \
    acc[7][3] = __builtin_amdgcn_mfma_f32_16x16x32_bf16(x3, b3, acc[7][3], 0, 0, 0); \
    __builtin_amdgcn_s_setprio(0);                                             \
    TAILVM;                                                                    \
    if (DO_READS) READS_BX8((tt) + 1);                                         \
    __builtin_amdgcn_s_barrier();                                              \
  } while (0)

__global__ __launch_bounds__(512, 2) void gemm_kernel(
    const __hip_bfloat16* __restrict__ Xb,  // [BATCH, KK]
    const __hip_bfloat16* __restrict__ W,   // [NN, KK], row n = o*16+l
    const float* __restrict__ g,            // [BATCH, NLEAF]
    const float* __restrict__ pb,           // [OUT_F, NLEAF]
    float* __restrict__ out) {              // [BATCH, OUT_F]
  extern __shared__ __align__(16) char smem[];  // 4 ring slots x 32 KB

  const int t    = threadIdx.x;
  const int lane = t & 63;
  const int w    = t >> 6;
  const int quad = lane >> 4;
  const int r16  = lane & 15;
  const int wr   = w >> 2;   // 0..1: A rows wr*128
  const int wc   = w & 3;    // 0..3: B rows (b-dir) wc*64
  const int swz  = (r16 >> 1) & 3;

  const int b0_ = blockIdx.x * BN;
  const int n0 = blockIdx.y * BM;

  const __hip_bfloat16* aG = W  + (long)n0 * KK;
  const __hip_bfloat16* bG = Xb + (long)b0_ * KK;

  // staging: 1024 16-B chunks per operand tile; chunk c -> row c>>2,
  // LDS phys slot c&3, GLOBAL slot (c&3)^((c>>3)&3)
  const int  c0 = t, c1 = t + 512;
  const long gOff0 = (long)(c0 >> 2) * KK + (long)(((c0 & 3) ^ ((c0 >> 3) & 3)) * 8);
  const long gOff1 = (long)(c1 >> 2) * KK + (long)(((c1 & 3) ^ ((c1 >> 3) & 3)) * 8);

  f32x4 acc[8][4] = {};
  bf16x8 a0, a1, a2, a3, b0, b1, b2, b3, x0, x1, x2, x3;

  // Prologue: fill 3 tiles of the ring; VM8 lands tile 0 (oldest 4 loads);
  // barrier publishes it; preload all 12 tile-0 frags in loop order [a,b,x].
  STAGE_AB(0, 0); STAGE_AB(1, 1); STAGE_AB(2, 2);
  VM8;
  __builtin_amdgcn_s_barrier();
  READS_A4(0);
  READS_BX8(0);

  // Steady state.  VM4 at tile t drains stage(t+1) (leaves stage(t+2)'s 4
  // and newer flying) -> barrier(t) publishes slot t+1... (one tile margin:
  // reads(t+1) issue in tile t AFTER barrier(t-1), whose VM4 drained
  // stage(t+1)).  Tail: VM0 at 29 publishes stage(31) for reads at 30.
  for (int tt = 0; tt < NKT - 3; ++tt)          // 0..28, stages 3..31
    TILE_BODY(tt, 1, VM4, 1);
  TILE_BODY(NKT - 3, 0, VM0, 1);                // 29
  TILE_BODY(NKT - 2, 0, NOVM, 1);               // 30
  TILE_BODY(NKT - 1, 0, NOVM, 0);               // 31

  // ---- stage g (transposed, padded) and pb into the (dead) slot-0 LDS ----
  // All frag reads drained by each wave's lgkmcnt(0) in tile 31 before the
  // final barrier, which orders them before these writes.
  float* gs  = (float*)smem;                       // [16][GS_PAD]
  float* pbs = (float*)(smem + 16 * GS_PAD * 4);   // [256]
#pragma unroll
  for (int j = 0; j < 8; ++j) {
    const int f = t + 512 * j;                     // 0..4095
    gs[(f & 15) * GS_PAD + (f >> 4)] = g[b0_ * NLEAF + f];
  }
  if (t < 256) pbs[t] = pb[(n0 >> 4) * NLEAF + t]; // o0 = n0/16; pb flat [o,l]
  __syncthreads();

  // ---- fused gated-reduction epilogue ----
  const int oBase = (n0 >> 4) + wr * 8;            // 8 consecutive o's (mi)
#pragma unroll
  for (int ni = 0; ni < 4; ++ni) {
    const int bl = wc * 64 + ni * 16 + r16;
    float gv[4];
#pragma unroll
    for (int r = 0; r < 4; ++r) gv[r] = gs[(quad * 4 + r) * GS_PAD + bl];
    float rv[8];
#pragma unroll
    for (int mi = 0; mi < 8; ++mi) {
      float v = 0.f;
#pragma unroll
      for (int r = 0; r < 4; ++r)
        v = fmaf(acc[mi][ni][r] + pbs[(wr * 8 + mi) * NLEAF + quad * 4 + r],
                 gv[r], v);
      v += __shfl_xor(v, 16);
      v += __shfl_xor(v, 32);                      // sum over quads -> sum_l
      rv[mi] = v;
    }
    if (quad == 0) {
      *(float4*)(out + (long)(b0_ + bl) * OUT_F + oBase) =
          make_float4(rv[0], rv[1], rv[2], rv[3]);
      *(float4*)(out + (long)(b0_ + bl) * OUT_F + oBase + 4) =
          make_float4(rv[4], rv[5], rv[6], rv[7]);
    }
  }
}

// ---------------------------------------------------------------------------
// Fallback (ws too small for packed buffers): slow but correct fp32 path.
// ---------------------------------------------------------------------------
__global__ __launch_bounds__(256) void gate_kernel_fb(
    const float* __restrict__ x, const float* __restrict__ gw,
    const float* __restrict__ gb, float* __restrict__ g) {
  const int lane = threadIdx.x & 63;
  const int wv   = threadIdx.x >> 6;
  const int b    = blockIdx.x * 4 + wv;
  const int i4   = lane >> 4;
  const int l    = lane & 15;
  const float* xrow = x + (size_t)b * IN_F;
  float acc = 0.f;
  for (int k = 0; k < IN_F / 4; ++k)
    acc = fmaf(xrow[k * 4 + i4], gw[k * 64 + lane], acc);
  acc += __shfl_xor(acc, 16);
  acc += __shfl_xor(acc, 32);
  float logit = acc + gb[l];
  float m = logit;
  for (int off = 8; off > 0; off >>= 1) m = fmaxf(m, __shfl_xor(m, off));
  float e = __expf(logit - m);
  float s = e;
  for (int off = 8; off > 0; off >>= 1) s += __shfl_xor(s, off);
  if (lane < NLEAF) g[b * NLEAF + l] = e / s;
}

__global__ __launch_bounds__(256) void fallback_kernel(
    const float* __restrict__ x, const float* __restrict__ pw,
    const float* __restrict__ pb, const float* __restrict__ g,
    float* __restrict__ out) {
  const int b = blockIdx.x;
  __shared__ float xs[IN_F];
  __shared__ float gsl[NLEAF];
  const int t = threadIdx.x;
  for (int j = t; j < IN_F; j += 256) xs[j] = x[(long)b * IN_F + j];
  if (t < NLEAF) gsl[t] = g[b * NLEAF + t];
  __syncthreads();
  for (int o = t; o < OUT_F; o += 256) {
    const float* pwo = pw + (long)o * (IN_F * NLEAF);
    float acc = 0.f;
    for (int i = 0; i < IN_F; ++i) {
      const float xv = xs[i];
      float wsum = 0.f;
#pragma unroll
      for (int l = 0; l < NLEAF; ++l) wsum += gsl[l] * pwo[i * NLEAF + l];
      acc += xv * wsum;
    }
    float bias = 0.f;
#pragma unroll
    for (int l = 0; l < NLEAF; ++l) bias += gsl[l] * pb[o * NLEAF + l];
    out[(long)b * OUT_F + o] = acc + bias;
  }
}

extern "C" void kernel_launch(void* const* d_in, const int* in_sizes, int n_in,
                              void* d_out, int out_size, void* d_ws, size_t ws_size,
                              hipStream_t stream) {
  const float* x  = (const float*)d_in[0];  // [4096,1024]
  const float* gw = (const float*)d_in[1];  // [1024,16]
  const float* gb = (const float*)d_in[2];  // [16]
  const float* pw = (const float*)d_in[3];  // [1024,1024,16]
  const float* pb = (const float*)d_in[4];  // [1024,16]
  float* out = (float*)d_out;               // [4096,1024]

  const size_t w_bytes  = (size_t)NN * KK * sizeof(__hip_bfloat16);    // 33.6 MB
  const size_t xb_bytes = (size_t)BATCH * KK * sizeof(__hip_bfloat16); //  8.4 MB
  const size_t g_bytes  = (size_t)BATCH * NLEAF * sizeof(float);       //  0.26 MB

  if (ws_size >= w_bytes + xb_bytes + g_bytes) {
    __hip_bfloat16* W  = (__hip_bfloat16*)d_ws;
    __hip_bfloat16* xb = (__hip_bfloat16*)((char*)d_ws + w_bytes);
    float*          g  = (float*)((char*)d_ws + w_bytes + xb_bytes);

    static int attr_done = 0;
    if (!attr_done) {
      // 128 KB dynamic LDS (> 64 KB default cap); gfx950 has 160 KB/CU.
      (void)hipFuncSetAttribute((const void*)gemm_kernel,
                                hipFuncAttributeMaxDynamicSharedMemorySize,
                                4 * SLICE);
      attr_done = 1;
    }

    prep_kernel<<<OUT_F + BATCH / 4, 256, 0, stream>>>(x, gw, gb, pw, g, xb, W);
    gemm_kernel<<<dim3(BATCH / BN, NN / BM), 512, 4 * SLICE, stream>>>(
        xb, W, g, pb, out);
  } else {
    float* g = (float*)d_ws;  // needs only 256 KB
    gate_kernel_fb<<<BATCH / 4, 256, 0, stream>>>(x, gw, gb, g);
    fallback_kernel<<<BATCH, 256, 0, stream>>>(x, pw, pb, g, out);
  }
}

// Round 6
// 249.085 us; speedup vs baseline: 1.0666x; 1.0666x over previous
//
#include <hip/hip_runtime.h>
#include <hip/hip_bf16.h>
#include <stdint.h>

// Problem constants (from reference)
#define IN_F   1024
#define OUT_F  1024
#define NLEAF  16
#define BATCH  4096

// GEMM C'[n, b] = sum_i W'[n,i] * Xb[b,i],  n = o*16+l  (n = C-tile ROW dim).
// R11: m201-style 8-phase schedule.  BK=64, 2 LDS buffers (64 KB each), each
// K-tile processed as 4 phases of 16 MFMA (quadrants: rowhalf x colhalf) with
// double-barrier per phase.  Operand regs reused across phases: A(rowhalf)
// read once serves 2 phases, B(colhalf) likewise -> reads/phase = 12,4,8,0.
// Staging: one half-tile (A0/A1/B0/B1 of kt+1) per phase, 2 gload_lds/thread;
// boundary vmcnt(0) at P3 (loads >=1 phase old, L2-resident) publishes kt+1.
// 8-slot K-swizzle: stage slot=(c&7)^((c>>3)&7) <-> read slot=(ks*4+quad)^
// (r16&7); conflict-free per 8-lane b128 groups (bank = 4*slot, 8 distinct).
#define KK      1024              // GEMM K = IN_F
#define NN      (OUT_F * NLEAF)   // 16384
#define BM      256               // n-tile
#define BN      256               // b-tile
#define BK      64
#define NKT     (KK / BK)         // 16 K-tiles
#define GS_PAD  257               // g-tile LDS row stride (conflict-free quads)

typedef __bf16 bf16x8 __attribute__((ext_vector_type(8)));
typedef float  f32x4  __attribute__((ext_vector_type(4)));

#define ASYNC_COPY16(gp, lp)                                                         \
  __builtin_amdgcn_global_load_lds((const __attribute__((address_space(1))) void*)(gp), \
                                   (__attribute__((address_space(3))) void*)(lp),       \
                                   16, 0, 0)

// ---------------------------------------------------------------------------
// Kernel 1: fused prep.  Blocks [0,1024): transpose/pack pw -> W'.
// Blocks [1024,2048): gating softmax + x->bf16 pack (4 batch rows/block).
// ---------------------------------------------------------------------------
__global__ __launch_bounds__(256) void prep_kernel(
    const float* __restrict__ x, const float* __restrict__ gw,
    const float* __restrict__ gb, const float* __restrict__ pw,
    float* __restrict__ g, __hip_bfloat16* __restrict__ xb,
    __hip_bfloat16* __restrict__ W) {
  __shared__ __align__(16) __hip_bfloat16 lt[16 * 264];
  const int t = threadIdx.x;

  if (blockIdx.x < OUT_F) {
    // ---- pack_w path: W'[o*16+l, i] = bf16(pw[o,i,l]) via LDS transpose ----
    const int o = blockIdx.x;
    const float* src = pw + (size_t)o * (IN_F * NLEAF);
    for (int ch = 0; ch < 4; ++ch) {
      const float4* p = (const float4*)(src + ch * 4096 + t * 16);  // i=t, 16 l
      const float4 v0 = p[0], v1 = p[1], v2 = p[2], v3 = p[3];
      if (ch) __syncthreads();   // prev readout done before overwriting lt
      lt[ 0 * 264 + t] = __float2bfloat16(v0.x);
      lt[ 1 * 264 + t] = __float2bfloat16(v0.y);
      lt[ 2 * 264 + t] = __float2bfloat16(v0.z);
      lt[ 3 * 264 + t] = __float2bfloat16(v0.w);
      lt[ 4 * 264 + t] = __float2bfloat16(v1.x);
      lt[ 5 * 264 + t] = __float2bfloat16(v1.y);
      lt[ 6 * 264 + t] = __float2bfloat16(v1.z);
      lt[ 7 * 264 + t] = __float2bfloat16(v1.w);
      lt[ 8 * 264 + t] = __float2bfloat16(v2.x);
      lt[ 9 * 264 + t] = __float2bfloat16(v2.y);
      lt[10 * 264 + t] = __float2bfloat16(v2.z);
      lt[11 * 264 + t] = __float2bfloat16(v2.w);
      lt[12 * 264 + t] = __float2bfloat16(v3.x);
      lt[13 * 264 + t] = __float2bfloat16(v3.y);
      lt[14 * 264 + t] = __float2bfloat16(v3.z);
      lt[15 * 264 + t] = __float2bfloat16(v3.w);
      __syncthreads();
#pragma unroll
      for (int jj = 0; jj < 2; ++jj) {
        const int u = t + 256 * jj;        // 512 uint4 per chunk
        const int l = u >> 5;
        const int i8 = (u & 31) * 8;
        *(uint4*)(W + ((size_t)o * NLEAF + l) * KK + ch * 256 + i8) =
            *(const uint4*)(lt + l * 264 + i8);
      }
    }
  } else {
    // ---- gate + pack_x path ----
    const int blk  = blockIdx.x - OUT_F;
    const int lane = t & 63;
    const int wv   = t >> 6;
    const int b    = blk * 4 + wv;
    const int i4   = lane >> 4;
    const int l    = lane & 15;

    const float* xrow = x + (size_t)b * IN_F;
    float acc = 0.f;
#pragma unroll 8
    for (int k = 0; k < IN_F / 4; ++k) {
      const float xv = xrow[k * 4 + i4];          // same addr per 16-group (L1)
      const float wvv = gw[k * 64 + lane];        // coalesced
      acc = fmaf(xv, wvv, acc);
    }
    acc += __shfl_xor(acc, 16);
    acc += __shfl_xor(acc, 32);
    float logit = acc + gb[l];
    float m = logit;
#pragma unroll
    for (int off = 8; off > 0; off >>= 1) m = fmaxf(m, __shfl_xor(m, off));
    float e = __expf(logit - m);
    float s = e;
#pragma unroll
    for (int off = 8; off > 0; off >>= 1) s += __shfl_xor(s, off);
    if (lane < NLEAF) g[b * NLEAF + l] = e / s;

    const float* xblk = x + (size_t)blk * 4 * IN_F;
    __hip_bfloat16* xbblk = xb + (size_t)blk * 4 * IN_F;
#pragma unroll
    for (int j = 0; j < 2; ++j) {
      const int f = (t + 256 * j) * 8;
      const float4 a0 = *(const float4*)(xblk + f);
      const float4 a1 = *(const float4*)(xblk + f + 4);
      __align__(16) __hip_bfloat16 tmp[8];
      tmp[0] = __float2bfloat16(a0.x); tmp[1] = __float2bfloat16(a0.y);
      tmp[2] = __float2bfloat16(a0.z); tmp[3] = __float2bfloat16(a0.w);
      tmp[4] = __float2bfloat16(a1.x); tmp[5] = __float2bfloat16(a1.y);
      tmp[6] = __float2bfloat16(a1.z); tmp[7] = __float2bfloat16(a1.w);
      *(uint4*)(xbblk + f) = *(const uint4*)tmp;
    }
  }
}

// ---------------------------------------------------------------------------
// Kernel 2: bf16 MFMA GEMM, 256x256 tile, BK=64, 8-phase 2-buffer pipeline.
// 512 threads = 8 waves (wr in {0,1} n-dir x wc in 0..3 b-dir); per-wave
// output 128x64.  acc[mi][ni][r] = C'[n = n0 + wr*128 + mi*16 + quad*4 + r]
// [b = b0 + wc*64 + ni*16 + r16]; l = quad*4+r, o = n/16.
// LDS (128 KB): buffer u at u*64KB: A-half0 | A-half1 | B-half0 | B-half1,
// each 128 rows x 128 B.  Wave reads only A-half(wr) and B-half(wc>>1).
// ---------------------------------------------------------------------------
#define STAGE_H(ktt, h)                                                        \
  do {                                                                         \
    char* _d = smem + (((ktt) & 1) * 65536) + (h) * 16384 + t * 16;            \
    const __hip_bfloat16* _s = (((h) < 2) ? aG : bG) +                         \
        (long)((h) & 1) * 131072 + (long)(ktt) * 64 + hOff;                    \
    ASYNC_COPY16(_s, _d);                                                      \
    ASYNC_COPY16(_s + 65536, _d + 8192);                                       \
  } while (0)

#define RD_A(U, RH)                                                            \
  do {                                                                         \
    const char* _ab = smem + (U) * 65536 + wrOff + (RH) * 8192 + r16 * 128;    \
    a00 = *(const bf16x8*)(_ab + kx0);                                         \
    a01 = *(const bf16x8*)(_ab + kx1);                                         \
    a10 = *(const bf16x8*)(_ab + 2048 + kx0);                                  \
    a11 = *(const bf16x8*)(_ab + 2048 + kx1);                                  \
    a20 = *(const bf16x8*)(_ab + 4096 + kx0);                                  \
    a21 = *(const bf16x8*)(_ab + 4096 + kx1);                                  \
    a30 = *(const bf16x8*)(_ab + 6144 + kx0);                                  \
    a31 = *(const bf16x8*)(_ab + 6144 + kx1);                                  \
  } while (0)

#define RD_B0(U)                                                               \
  do {                                                                         \
    const char* _bb = smem + (U) * 65536 + 32768 + bOff + r16 * 128;           \
    b00 = *(const bf16x8*)(_bb + kx0);                                         \
    b01 = *(const bf16x8*)(_bb + kx1);                                         \
    b10 = *(const bf16x8*)(_bb + 2048 + kx0);                                  \
    b11 = *(const bf16x8*)(_bb + 2048 + kx1);                                  \
  } while (0)

#define RD_B1(U)                                                               \
  do {                                                                         \
    const char* _bb = smem + (U) * 65536 + 32768 + bOff + r16 * 128;           \
    b20 = *(const bf16x8*)(_bb + 4096 + kx0);                                  \
    b21 = *(const bf16x8*)(_bb + 4096 + kx1);                                  \
    b30 = *(const bf16x8*)(_bb + 6144 + kx0);                                  \
    b31 = *(const bf16x8*)(_bb + 6144 + kx1);                                  \
  } while (0)

// 16 MFMA = quadrant (rowhalf RH, colhalf 0): 8 independent ks0 then 8 ks1.
#define MM_C0(RH)                                                              \
    acc[(RH)*4+0][0] = __builtin_amdgcn_mfma_f32_16x16x32_bf16(a00, b00, acc[(RH)*4+0][0], 0, 0, 0); \
    acc[(RH)*4+0][1] = __builtin_amdgcn_mfma_f32_16x16x32_bf16(a00, b10, acc[(RH)*4+0][1], 0, 0, 0); \
    acc[(RH)*4+1][0] = __builtin_amdgcn_mfma_f32_16x16x32_bf16(a10, b00, acc[(RH)*4+1][0], 0, 0, 0); \
    acc[(RH)*4+1][1] = __builtin_amdgcn_mfma_f32_16x16x32_bf16(a10, b10, acc[(RH)*4+1][1], 0, 0, 0); \
    acc[(RH)*4+2][0] = __builtin_amdgcn_mfma_f32_16x16x32_bf16(a20, b00, acc[(RH)*4+2][0], 0, 0, 0); \
    acc[(RH)*4+2][1] = __builtin_amdgcn_mfma_f32_16x16x32_bf16(a20, b10, acc[(RH)*4+2][1], 0, 0, 0); \
    acc[(RH)*4+3][0] = __builtin_amdgcn_mfma_f32_16x16x32_bf16(a30, b00, acc[(RH)*4+3][0], 0, 0, 0); \
    acc[(RH)*4+3][1] = __builtin_amdgcn_mfma_f32_16x16x32_bf16(a30, b10, acc[(RH)*4+3][1], 0, 0, 0); \
    acc[(RH)*4+0][0] = __builtin_amdgcn_mfma_f32_16x16x32_bf16(a01, b01, acc[(RH)*4+0][0], 0, 0, 0); \
    acc[(RH)*4+0][1] = __builtin_amdgcn_mfma_f32_16x16x32_bf16(a01, b11, acc[(RH)*4+0][1], 0, 0, 0); \
    acc[(RH)*4+1][0] = __builtin_amdgcn_mfma_f32_16x16x32_bf16(a11, b01, acc[(RH)*4+1][0], 0, 0, 0); \
    acc[(RH)*4+1][1] = __builtin_amdgcn_mfma_f32_16x16x32_bf16(a11, b11, acc[(RH)*4+1][1], 0, 0, 0); \
    acc[(RH)*4+2][0] = __builtin_amdgcn_mfma_f32_16x16x32_bf16(a21, b01, acc[(RH)*4+2][0], 0, 0, 0); \
    acc[(RH)*4+2][1] = __builtin_amdgcn_mfma_f32_16x16x32_bf16(a21, b11, acc[(RH)*4+2][1], 0, 0, 0); \
    acc[(RH)*4+3][0] = __builtin_amdgcn_mfma_f32_16x16x32_bf16(a31, b01, acc[(RH)*4+3][0], 0, 0, 0); \
    acc[(RH)*4+3][1] = __builtin_amdgcn_mfma_f32_16x16x32_bf16(a31, b11, acc[(RH)*4+3][1], 0, 0, 0);

// quadrant (RH, colhalf 1)
#define MM_C1(RH)                                                              \
    acc[(RH)*4+0][2] = __builtin_amdgcn_mfma_f32_16x16x32_bf16(a00, b20, acc[(RH)*4+0][2], 0, 0, 0); \
    acc[(RH)*4+0][3] = __builtin_amdgcn_mfma_f32_16x16x32_bf16(a00, b30, acc[(RH)*4+0][3], 0, 0, 0); \
    acc[(RH)*4+1][2] = __builtin_amdgcn_mfma_f32_16x16x32_bf16(a10, b20, acc[(RH)*4+1][2], 0, 0, 0); \
    acc[(RH)*4+1][3] = __builtin_amdgcn_mfma_f32_16x16x32_bf16(a10, b30, acc[(RH)*4+1][3], 0, 0, 0); \
    acc[(RH)*4+2][2] = __builtin_amdgcn_mfma_f32_16x16x32_bf16(a20, b20, acc[(RH)*4+2][2], 0, 0, 0); \
    acc[(RH)*4+2][3] = __builtin_amdgcn_mfma_f32_16x16x32_bf16(a20, b30, acc[(RH)*4+2][3], 0, 0, 0); \
    acc[(RH)*4+3][2] = __builtin_amdgcn_mfma_f32_16x16x32_bf16(a30, b20, acc[(RH)*4+3][2], 0, 0, 0); \
    acc[(RH)*4+3][3] = __builtin_amdgcn_mfma_f32_16x16x32_bf16(a30, b30, acc[(RH)*4+3][3], 0, 0, 0); \
    acc[(RH)*4+0][2] = __builtin_amdgcn_mfma_f32_16x16x32_bf16(a01, b21, acc[(RH)*4+0][2], 0, 0, 0); \
    acc[(RH)*4+0][3] = __builtin_amdgcn_mfma_f32_16x16x32_bf16(a01, b31, acc[(RH)*4+0][3], 0, 0, 0); \
    acc[(RH)*4+1][2] = __builtin_amdgcn_mfma_f32_16x16x32_bf16(a11, b21, acc[(RH)*4+1][2], 0, 0, 0); \
    acc[(RH)*4+1][3] = __builtin_amdgcn_mfma_f32_16x16x32_bf16(a11, b31, acc[(RH)*4+1][3], 0, 0, 0); \
    acc[(RH)*4+2][2] = __builtin_amdgcn_mfma_f32_16x16x32_bf16(a21, b21, acc[(RH)*4+2][2], 0, 0, 0); \
    acc[(RH)*4+2][3] = __builtin_amdgcn_mfma_f32_16x16x32_bf16(a21, b31, acc[(RH)*4+2][3], 0, 0, 0); \
    acc[(RH)*4+3][2] = __builtin_amdgcn_mfma_f32_16x16x32_bf16(a31, b21, acc[(RH)*4+3][2], 0, 0, 0); \
    acc[(RH)*4+3][3] = __builtin_amdgcn_mfma_f32_16x16x32_bf16(a31, b31, acc[(RH)*4+3][3], 0, 0, 0);

#define PHASE_SYNC                                                             \
    __builtin_amdgcn_s_barrier();                                              \
    asm volatile("s_waitcnt lgkmcnt(0)" ::: "memory");                         \
    __builtin_amdgcn_sched_barrier(0);

// One K-tile = 4 phases.  Reads/phase: 12, 4, 8, 0.  Stage one half-tile of
// kt+1 per phase; boundary vmcnt(0)+barrier at P3 publishes kt+1's buffer.
#define KTILE(kt, U, DOSTAGE, DOVM)                                            \
  do {                                                                         \
    /* P0: quadrant (rh0, ch0) */                                              \
    RD_A(U, 0);                                                                \
    RD_B0(U);                                                                  \
    if (DOSTAGE) STAGE_H((kt) + 1, 0);                                         \
    PHASE_SYNC;                                                                \
    __builtin_amdgcn_s_setprio(1);                                             \
    MM_C0(0);                                                                  \
    __builtin_amdgcn_s_setprio(0);                                             \
    __builtin_amdgcn_s_barrier();                                              \
    /* P1: quadrant (rh0, ch1) — A regs reused */                              \
    RD_B1(U);                                                                  \
    if (DOSTAGE) STAGE_H((kt) + 1, 1);                                         \
    PHASE_SYNC;                                                                \
    __builtin_amdgcn_s_setprio(1);                                             \
    MM_C1(0);                                                                  \
    __builtin_amdgcn_s_setprio(0);                                             \
    __builtin_amdgcn_s_barrier();                                              \
    /* P2: quadrant (rh1, ch0) — B0 regs reused, A overwritten */              \
    RD_A(U, 1);                                                                \
    if (DOSTAGE) STAGE_H((kt) + 1, 2);                                         \
    PHASE_SYNC;                                                                \
    __builtin_amdgcn_s_setprio(1);                                             \
    MM_C0(1);                                                                  \
    __builtin_amdgcn_s_setprio(0);                                             \
    __builtin_amdgcn_s_barrier();                                              \
    /* P3: quadrant (rh1, ch1) — no reads; boundary vmcnt */                   \
    if (DOSTAGE) STAGE_H((kt) + 1, 3);                                         \
    __builtin_amdgcn_s_barrier();                                              \
    __builtin_amdgcn_s_setprio(1);                                             \
    MM_C1(1);                                                                  \
    __builtin_amdgcn_s_setprio(0);                                             \
    if (DOVM) { asm volatile("s_waitcnt vmcnt(0)" ::: "memory"); }             \
    __builtin_amdgcn_s_barrier();                                              \
  } while (0)

__global__ __launch_bounds__(512, 2) void gemm_kernel(
    const __hip_bfloat16* __restrict__ Xb,  // [BATCH, KK]
    const __hip_bfloat16* __restrict__ W,   // [NN, KK], row n = o*16+l
    const float* __restrict__ g,            // [BATCH, NLEAF]
    const float* __restrict__ pb,           // [OUT_F, NLEAF]
    float* __restrict__ out) {              // [BATCH, OUT_F]
  extern __shared__ __align__(16) char smem[];  // 2 buffers x 64 KB

  const int t    = threadIdx.x;
  const int lane = t & 63;
  const int w    = t >> 6;
  const int quad = lane >> 4;
  const int r16  = lane & 15;
  const int wr   = w >> 2;   // 0..1: A rows wr*128 (= A-half index)
  const int wc   = w & 3;    // 0..3: B rows (b-dir) wc*64

  const int b0_ = blockIdx.x * BN;
  const int n0  = blockIdx.y * BM;

  const __hip_bfloat16* aG = W  + (long)n0 * KK;
  const __hip_bfloat16* bG = Xb + (long)b0_ * KK;

  // staging: half-tile = 128 rows x 128 B = 1024 chunks of 16 B; thread t
  // handles chunks t and t+512.  LDS linear; global K-slot = (c&7)^(row&7).
  const long hOff = (long)(t >> 3) * 1024 + (long)(((t & 7) ^ ((t >> 3) & 7)) * 8);

  // fragment read constants: slot byte = ((ks*4+quad)^(r16&7))*16
  const int kx0 = (quad ^ (r16 & 7)) * 16;
  const int kx1 = kx0 ^ 64;
  const int wrOff = wr * 16384;
  const int bOff  = (wc >> 1) * 16384 + (wc & 1) * 8192;

  f32x4 acc[8][4] = {};
  bf16x8 a00, a01, a10, a11, a20, a21, a30, a31;
  bf16x8 b00, b01, b10, b11, b20, b21, b30, b31;

  // Prologue: stage K-tile 0's 4 half-tiles into buffer 0; drain; publish.
  STAGE_H(0, 0); STAGE_H(0, 1); STAGE_H(0, 2); STAGE_H(0, 3);
  asm volatile("s_waitcnt vmcnt(0)" ::: "memory");
  __builtin_amdgcn_s_barrier();

  for (int kt = 0; kt < NKT - 2; kt += 2) {
    KTILE(kt, 0, 1, 1);
    KTILE(kt + 1, 1, 1, 1);
  }
  KTILE(NKT - 2, 0, 1, 1);
  KTILE(NKT - 1, 1, 0, 0);

  // ---- stage g (transposed, padded) and pb into the (dead) buffer-0 LDS ----
  // All frag reads drained by per-phase lgkmcnt(0) before the final barrier.
  float* gs  = (float*)smem;                       // [16][GS_PAD]
  float* pbs = (float*)(smem + 16 * GS_PAD * 4);   // [256]
#pragma unroll
  for (int j = 0; j < 8; ++j) {
    const int f = t + 512 * j;                     // 0..4095
    gs[(f & 15) * GS_PAD + (f >> 4)] = g[b0_ * NLEAF + f];
  }
  if (t < 256) pbs[t] = pb[(n0 >> 4) * NLEAF + t]; // o0 = n0/16; pb flat [o,l]
  __syncthreads();

  // ---- fused gated-reduction epilogue ----
  const int oBase = (n0 >> 4) + wr * 8;            // 8 consecutive o's (mi)
#pragma unroll
  for (int ni = 0; ni < 4; ++ni) {
    const int bl = wc * 64 + ni * 16 + r16;
    float gv[4];
#pragma unroll
    for (int r = 0; r < 4; ++r) gv[r] = gs[(quad * 4 + r) * GS_PAD + bl];
    float rv[8];
#pragma unroll
    for (int mi = 0; mi < 8; ++mi) {
      float v = 0.f;
#pragma unroll
      for (int r = 0; r < 4; ++r)
        v = fmaf(acc[mi][ni][r] + pbs[(wr * 8 + mi) * NLEAF + quad * 4 + r],
                 gv[r], v);
      v += __shfl_xor(v, 16);
      v += __shfl_xor(v, 32);                      // sum over quads -> sum_l
      rv[mi] = v;
    }
    if (quad == 0) {
      *(float4*)(out + (long)(b0_ + bl) * OUT_F + oBase) =
          make_float4(rv[0], rv[1], rv[2], rv[3]);
      *(float4*)(out + (long)(b0_ + bl) * OUT_F + oBase + 4) =
          make_float4(rv[4], rv[5], rv[6], rv[7]);
    }
  }
}

// ---------------------------------------------------------------------------
// Fallback (ws too small for packed buffers): slow but correct fp32 path.
// ---------------------------------------------------------------------------
__global__ __launch_bounds__(256) void gate_kernel_fb(
    const float* __restrict__ x, const float* __restrict__ gw,
    const float* __restrict__ gb, float* __restrict__ g) {
  const int lane = threadIdx.x & 63;
  const int wv   = threadIdx.x >> 6;
  const int b    = blockIdx.x * 4 + wv;
  const int i4   = lane >> 4;
  const int l    = lane & 15;
  const float* xrow = x + (size_t)b * IN_F;
  float acc = 0.f;
  for (int k = 0; k < IN_F / 4; ++k)
    acc = fmaf(xrow[k * 4 + i4], gw[k * 64 + lane], acc);
  acc += __shfl_xor(acc, 16);
  acc += __shfl_xor(acc, 32);
  float logit = acc + gb[l];
  float m = logit;
  for (int off = 8; off > 0; off >>= 1) m = fmaxf(m, __shfl_xor(m, off));
  float e = __expf(logit - m);
  float s = e;
  for (int off = 8; off > 0; off >>= 1) s += __shfl_xor(s, off);
  if (lane < NLEAF) g[b * NLEAF + l] = e / s;
}

__global__ __launch_bounds__(256) void fallback_kernel(
    const float* __restrict__ x, const float* __restrict__ pw,
    const float* __restrict__ pb, const float* __restrict__ g,
    float* __restrict__ out) {
  const int b = blockIdx.x;
  __shared__ float xs[IN_F];
  __shared__ float gsl[NLEAF];
  const int t = threadIdx.x;
  for (int j = t; j < IN_F; j += 256) xs[j] = x[(long)b * IN_F + j];
  if (t < NLEAF) gsl[t] = g[b * NLEAF + t];
  __syncthreads();
  for (int o = t; o < OUT_F; o += 256) {
    const float* pwo = pw + (long)o * (IN_F * NLEAF);
    float acc = 0.f;
    for (int i = 0; i < IN_F; ++i) {
      const float xv = xs[i];
      float wsum = 0.f;
#pragma unroll
      for (int l = 0; l < NLEAF; ++l) wsum += gsl[l] * pwo[i * NLEAF + l];
      acc += xv * wsum;
    }
    float bias = 0.f;
#pragma unroll
    for (int l = 0; l < NLEAF; ++l) bias += gsl[l] * pb[o * NLEAF + l];
    out[(long)b * OUT_F + o] = acc + bias;
  }
}

extern "C" void kernel_launch(void* const* d_in, const int* in_sizes, int n_in,
                              void* d_out, int out_size, void* d_ws, size_t ws_size,
                              hipStream_t stream) {
  const float* x  = (const float*)d_in[0];  // [4096,1024]
  const float* gw = (const float*)d_in[1];  // [1024,16]
  const float* gb = (const float*)d_in[2];  // [16]
  const float* pw = (const float*)d_in[3];  // [1024,1024,16]
  const float* pb = (const float*)d_in[4];  // [1024,16]
  float* out = (float*)d_out;               // [4096,1024]

  const size_t w_bytes  = (size_t)NN * KK * sizeof(__hip_bfloat16);    // 33.6 MB
  const size_t xb_bytes = (size_t)BATCH * KK * sizeof(__hip_bfloat16); //  8.4 MB
  const size_t g_bytes  = (size_t)BATCH * NLEAF * sizeof(float);       //  0.26 MB

  if (ws_size >= w_bytes + xb_bytes + g_bytes) {
    __hip_bfloat16* W  = (__hip_bfloat16*)d_ws;
    __hip_bfloat16* xb = (__hip_bfloat16*)((char*)d_ws + w_bytes);
    float*          g  = (float*)((char*)d_ws + w_bytes + xb_bytes);

    static int attr_done = 0;
    if (!attr_done) {
      // 128 KB dynamic LDS (> 64 KB default cap); gfx950 has 160 KB/CU.
      (void)hipFuncSetAttribute((const void*)gemm_kernel,
                                hipFuncAttributeMaxDynamicSharedMemorySize,
                                131072);
      attr_done = 1;
    }

    prep_kernel<<<OUT_F + BATCH / 4, 256, 0, stream>>>(x, gw, gb, pw, g, xb, W);
    gemm_kernel<<<dim3(BATCH / BN, NN / BM), 512, 131072, stream>>>(
        xb, W, g, pb, out);
  } else {
    float* g = (float*)d_ws;  // needs only 256 KB
    gate_kernel_fb<<<BATCH / 4, 256, 0, stream>>>(x, gw, gb, g);
    fallback_kernel<<<BATCH, 256, 0, stream>>>(x, pw, pb, g, out);
  }
}